// Round 3
// baseline (204.394 us; speedup 1.0000x reference)
//
#include <hip/hip_runtime.h>

#define LOG2E 1.4426950408889634f

typedef __bf16 bf16x8 __attribute__((ext_vector_type(8)));
typedef float f32x4 __attribute__((ext_vector_type(4)));

#define BB 2
#define NN 2048
#define CC 384
#define NH 12
#define HD 32
#define MROWS (BB * NN)   /* 4096 */

__device__ __forceinline__ unsigned short f2bf(float f) {
  __bf16 h = (__bf16)f;
  return __builtin_bit_cast(unsigned short, h);
}

__device__ __forceinline__ bf16x8 ldg_bf8(const unsigned short* p) {
  uint4 v = *reinterpret_cast<const uint4*>(p);
  return __builtin_bit_cast(bf16x8, v);
}

// ---------------- prep: fp32->bf16 casts + bias/scale prefolds ----------------
__global__ __launch_bounds__(256) void prep_kernel(
    const float* __restrict__ x, const float* __restrict__ q_w,
    const float* __restrict__ kv_w, const float* __restrict__ proj_w,
    const float* __restrict__ pos_bias, const float* __restrict__ temperature,
    unsigned short* __restrict__ xb, unsigned short* __restrict__ qwb,
    unsigned short* __restrict__ kvwb, unsigned short* __restrict__ pwb,
    float* __restrict__ bias2, float* __restrict__ scales) {
  long i = (long)blockIdx.x * blockDim.x + threadIdx.x;
  const long NX = (long)MROWS * CC;   // 1572864
  const long NQW = CC * CC;           // 147456
  const long NKV = 2 * CC * CC;       // 294912
  const long NPW = CC * CC;           // 147456
  const long NBI = NH * NN;           // 24576
  if (i < NX) { xb[i] = f2bf(x[i]); return; }
  i -= NX;
  if (i < NQW) { qwb[i] = f2bf(q_w[i]); return; }
  i -= NQW;
  if (i < NKV) { kvwb[i] = f2bf(kv_w[i]); return; }
  i -= NKV;
  if (i < NPW) { pwb[i] = f2bf(proj_w[i]); return; }
  i -= NPW;
  if (i < NBI) { bias2[i] = pos_bias[i] * LOG2E; return; }
  i -= NBI;
  if (i < NH) {
    float t = temperature[i];
    // softplus(t) * ln(N) * log2(e) = softplus(t) * log2(2048) = softplus(t)*11
    scales[i] = log1pf(expf(t)) * 11.0f;
  }
}

// ------- fused QKV GEMM + l2norm + layout: Qs,Kn=(b,h,n,d), VT=(b,h,d,n) -----
// Grid (64, NH). Wave = 16 rows x 96 cols (q|k|v 32-col slices of head h).
__global__ __launch_bounds__(256, 3) void gemm_qkv_norm_kernel(
    const unsigned short* __restrict__ xb, const unsigned short* __restrict__ qwb,
    const unsigned short* __restrict__ kvwb, const float* __restrict__ q_b,
    const float* __restrict__ kv_b, const float* __restrict__ qe,
    const float* __restrict__ scales, unsigned short* __restrict__ Qs,
    unsigned short* __restrict__ Kn, unsigned short* __restrict__ VT) {
  int wave = threadIdx.x >> 6;
  int lane = threadIdx.x & 63;
  int c = lane & 15, quad = lane >> 4;
  int h = blockIdx.y;
  int m0 = blockIdx.x * 64 + wave * 16;
  const unsigned short* arow = xb + (long)(m0 + c) * CC + quad * 8;
  const unsigned short* brow[6];
  brow[0] = qwb + (long)(h * 32 + c) * CC + quad * 8;
  brow[1] = qwb + (long)(h * 32 + 16 + c) * CC + quad * 8;
  brow[2] = kvwb + (long)(h * 32 + c) * CC + quad * 8;
  brow[3] = kvwb + (long)(h * 32 + 16 + c) * CC + quad * 8;
  brow[4] = kvwb + (long)(CC + h * 32 + c) * CC + quad * 8;
  brow[5] = kvwb + (long)(CC + h * 32 + 16 + c) * CC + quad * 8;

  f32x4 acc[6] = {};
  bf16x8 ac = ldg_bf8(arow);
  bf16x8 bc[6];
#pragma unroll
  for (int t = 0; t < 6; ++t) bc[t] = ldg_bf8(brow[t]);
  for (int kk = 0; kk < CC; kk += 32) {
    bf16x8 an;
    bf16x8 bn[6];
    if (kk + 32 < CC) {
      an = ldg_bf8(arow + kk + 32);
#pragma unroll
      for (int t = 0; t < 6; ++t) bn[t] = ldg_bf8(brow[t] + kk + 32);
    }
#pragma unroll
    for (int t = 0; t < 6; ++t)
      acc[t] = __builtin_amdgcn_mfma_f32_16x16x32_bf16(ac, bc[t], acc[t], 0, 0, 0);
    ac = an;
#pragma unroll
    for (int t = 0; t < 6; ++t) bc[t] = bn[t];
  }

  // epilogue: bias + l2norm(q,k) + qe/scale + stores
  float qb0 = q_b[h * 32 + c], qb1 = q_b[h * 32 + 16 + c];
  float kb0 = kv_b[h * 32 + c], kb1 = kv_b[h * 32 + 16 + c];
  float vb0 = kv_b[CC + h * 32 + c], vb1 = kv_b[CC + h * 32 + 16 + c];
  float qe0 = qe[h * HD + c], qe1 = qe[h * HD + 16 + c];
  float sc = scales[h];
  int b = m0 >> 11;
  int nb = (m0 & 2047) + quad * 4;
  int pair = b * NH + h;
  unsigned short* qsb = Qs + ((long)pair * NN + nb) * HD;
  unsigned short* knb = Kn + ((long)pair * NN + nb) * HD;
  ushort4 vp0, vp1;
#pragma unroll
  for (int r = 0; r < 4; ++r) {
    float q0 = acc[0][r] + qb0, q1 = acc[1][r] + qb1;
    float k0 = acc[2][r] + kb0, k1 = acc[3][r] + kb1;
    float v0 = acc[4][r] + vb0, v1 = acc[5][r] + vb1;
    float qs = q0 * q0 + q1 * q1, ks = k0 * k0 + k1 * k1;
#pragma unroll
    for (int off = 8; off; off >>= 1) {
      qs += __shfl_xor(qs, off);
      ks += __shfl_xor(ks, off);
    }
    float qi = 1.0f / fmaxf(sqrtf(qs), 1e-12f);
    float ki = 1.0f / fmaxf(sqrtf(ks), 1e-12f);
    qsb[r * HD + c] = f2bf((q0 * qi + qe0) * sc);
    qsb[r * HD + 16 + c] = f2bf((q1 * qi + qe1) * sc);
    knb[r * HD + c] = f2bf(k0 * ki);
    knb[r * HD + 16 + c] = f2bf(k1 * ki);
    ((unsigned short*)&vp0)[r] = f2bf(v0);
    ((unsigned short*)&vp1)[r] = f2bf(v1);
  }
  *reinterpret_cast<ushort4*>(VT + ((long)pair * HD + c) * NN + nb) = vp0;
  *reinterpret_cast<ushort4*>(VT + ((long)pair * HD + 16 + c) * NN + nb) = vp1;
}

// ---------------- flash attention, register-double-buffered K/V/bias ---------
__global__ __launch_bounds__(256, 3) void attn_kernel(
    const unsigned short* __restrict__ Qs, const unsigned short* __restrict__ Kn,
    const unsigned short* __restrict__ VT, const float* __restrict__ bias2,
    unsigned short* __restrict__ ao) {
  __shared__ unsigned short Pbuf[4][16][72];  // per-wave P tile, +8 pad
  int wave = threadIdx.x >> 6;
  int lane = threadIdx.x & 63;
  int c = lane & 15, quad = lane >> 4;
  int pair = blockIdx.y;  // b*NH + h
  int h = pair % NH;
  int b = pair / NH;
  const unsigned short* Qp = Qs + (long)pair * NN * HD;
  const unsigned short* Kp = Kn + (long)pair * NN * HD;
  const unsigned short* Vp = VT + (long)pair * HD * NN;
  const float* bp = bias2 + h * NN;
  int q0 = blockIdx.x * 64 + wave * 16;
  bf16x8 qf = ldg_bf8(Qp + (long)(q0 + c) * HD + quad * 8);
  f32x4 o0 = {}, o1 = {};
  float rs[4] = {};
  unsigned short(*pb)[72] = Pbuf[wave];

  bf16x8 kfa[4], vfa[4], kfb[4], vfb[4];
  float bva[4], bvb[4];

  auto loadk = [&](bf16x8(&kf)[4], bf16x8(&vf)[4], float(&bv)[4], int kb) {
#pragma unroll
    for (int t = 0; t < 4; ++t) {
      kf[t] = ldg_bf8(Kp + (long)(kb + t * 16 + c) * HD + quad * 8);
      bv[t] = bp[kb + t * 16 + c];
    }
#pragma unroll
    for (int ch = 0; ch < 2; ++ch) {
      vf[ch * 2] = ldg_bf8(Vp + (long)c * NN + kb + ch * 32 + quad * 8);
      vf[ch * 2 + 1] = ldg_bf8(Vp + (long)(c + 16) * NN + kb + ch * 32 + quad * 8);
    }
  };

  auto compute = [&](const bf16x8(&kf)[4], const bf16x8(&vf)[4], const float(&bv)[4]) {
    f32x4 s[4];
#pragma unroll
    for (int t = 0; t < 4; ++t) {
      f32x4 z = {};
      s[t] = __builtin_amdgcn_mfma_f32_16x16x32_bf16(qf, kf[t], z, 0, 0, 0);
    }
#pragma unroll
    for (int r = 0; r < 4; ++r) {
      float p0 = exp2f(s[0][r] + bv[0]);
      float p1 = exp2f(s[1][r] + bv[1]);
      float p2 = exp2f(s[2][r] + bv[2]);
      float p3 = exp2f(s[3][r] + bv[3]);
      rs[r] += (p0 + p1) + (p2 + p3);
      int row = quad * 4 + r;
      pb[row][c] = f2bf(p0);
      pb[row][16 + c] = f2bf(p1);
      pb[row][32 + c] = f2bf(p2);
      pb[row][48 + c] = f2bf(p3);
    }
#pragma unroll
    for (int ch = 0; ch < 2; ++ch) {
      bf16x8 pf = __builtin_bit_cast(
          bf16x8, *reinterpret_cast<const uint4*>(&pb[c][ch * 32 + quad * 8]));
      o0 = __builtin_amdgcn_mfma_f32_16x16x32_bf16(pf, vf[ch * 2], o0, 0, 0, 0);
      o1 = __builtin_amdgcn_mfma_f32_16x16x32_bf16(pf, vf[ch * 2 + 1], o1, 0, 0, 0);
    }
  };

  loadk(kfa, vfa, bva, 0);
#pragma unroll 1
  for (int k0 = 0; k0 < NN; k0 += 128) {
    loadk(kfb, vfb, bvb, k0 + 64);
    compute(kfa, vfa, bva);
    if (k0 + 128 < NN) loadk(kfa, vfa, bva, k0 + 128);
    compute(kfb, vfb, bvb);
  }

#pragma unroll
  for (int r = 0; r < 4; ++r) {
    float l = rs[r];
    l += __shfl_xor(l, 1, 16);
    l += __shfl_xor(l, 2, 16);
    l += __shfl_xor(l, 4, 16);
    l += __shfl_xor(l, 8, 16);
    float inv = 1.0f / l;
    int q = q0 + quad * 4 + r;
    unsigned short* op = ao + (long)(b * NN + q) * CC + h * HD;
    op[c] = f2bf(o0[r] * inv);
    op[c + 16] = f2bf(o1[r] * inv);
  }
}

// ---------------- proj: out = attn_out @ proj_w^T + proj_b (fp32 out) --------
__global__ __launch_bounds__(256) void proj_kernel(
    const unsigned short* __restrict__ ab, const unsigned short* __restrict__ pwb,
    const float* __restrict__ proj_b, float* __restrict__ out) {
  int wave = threadIdx.x >> 6;
  int lane = threadIdx.x & 63;
  int c = lane & 15, quad = lane >> 4;
  int m0 = blockIdx.x * 64 + wave * 16;
  int n0 = blockIdx.y * 64;
  const unsigned short* arow = ab + (long)(m0 + c) * CC + quad * 8;
  const unsigned short* brow[4];
#pragma unroll
  for (int t = 0; t < 4; ++t)
    brow[t] = pwb + (long)(n0 + t * 16 + c) * CC + quad * 8;
  f32x4 acc[4] = {};
  bf16x8 ac = ldg_bf8(arow);
  bf16x8 bc[4];
#pragma unroll
  for (int t = 0; t < 4; ++t) bc[t] = ldg_bf8(brow[t]);
  for (int kk = 0; kk < CC; kk += 32) {
    bf16x8 an;
    bf16x8 bn[4];
    if (kk + 32 < CC) {
      an = ldg_bf8(arow + kk + 32);
#pragma unroll
      for (int t = 0; t < 4; ++t) bn[t] = ldg_bf8(brow[t] + kk + 32);
    }
#pragma unroll
    for (int t = 0; t < 4; ++t)
      acc[t] = __builtin_amdgcn_mfma_f32_16x16x32_bf16(ac, bc[t], acc[t], 0, 0, 0);
    ac = an;
#pragma unroll
    for (int t = 0; t < 4; ++t) bc[t] = bn[t];
  }
#pragma unroll
  for (int t = 0; t < 4; ++t) {
    int o = n0 + t * 16 + c;
    float bv = proj_b[o];
#pragma unroll
    for (int r = 0; r < 4; ++r) {
      out[(long)(m0 + quad * 4 + r) * CC + o] = acc[t][r] + bv;
    }
  }
}

extern "C" void kernel_launch(void* const* d_in, const int* in_sizes, int n_in,
                              void* d_out, int out_size, void* d_ws, size_t ws_size,
                              hipStream_t stream) {
  const float* x = (const float*)d_in[0];
  const float* q_w = (const float*)d_in[1];
  const float* q_b = (const float*)d_in[2];
  const float* kv_w = (const float*)d_in[3];
  const float* kv_b = (const float*)d_in[4];
  const float* qe = (const float*)d_in[5];
  const float* temp = (const float*)d_in[6];
  const float* pos_bias = (const float*)d_in[7];
  const float* proj_w = (const float*)d_in[8];
  const float* proj_b = (const float*)d_in[9];
  float* out = (float*)d_out;

  char* ws = (char*)d_ws;
  unsigned short* xb = (unsigned short*)(ws + 0);          // 3,145,728 B
  unsigned short* qwb = (unsigned short*)(ws + 3145728);   //   294,912 B
  unsigned short* kvwb = (unsigned short*)(ws + 3440640);  //   589,824 B
  unsigned short* pwb = (unsigned short*)(ws + 4030464);   //   294,912 B
  float* bias2 = (float*)(ws + 4325376);                   //    98,304 B
  float* scales = (float*)(ws + 4423680);                  //       256 B
  unsigned short* Qs = (unsigned short*)(ws + 4423936);    // 3,145,728 B
  unsigned short* Kn = (unsigned short*)(ws + 7569664);    // 3,145,728 B
  unsigned short* VT = (unsigned short*)(ws + 10715392);   // 3,145,728 B
  unsigned short* ao = (unsigned short*)(ws + 13861120);   // 3,145,728 B -> 17 MB

  prep_kernel<<<8545, 256, 0, stream>>>(x, q_w, kv_w, proj_w, pos_bias, temp, xb,
                                        qwb, kvwb, pwb, bias2, scales);
  gemm_qkv_norm_kernel<<<dim3(64, NH), 256, 0, stream>>>(xb, qwb, kvwb, q_b, kv_b,
                                                         qe, scales, Qs, Kn, VT);
  attn_kernel<<<dim3(32, 24), 256, 0, stream>>>(Qs, Kn, VT, bias2, ao);
  proj_kernel<<<dim3(64, 6), 256, 0, stream>>>(ao, pwb, proj_b, out);
}